// Round 1
// baseline (384.433 us; speedup 1.0000x reference)
//
#include <hip/hip_runtime.h>

typedef __attribute__((ext_vector_type(8))) short short8;
typedef __attribute__((ext_vector_type(8))) unsigned short ushort8;
typedef __attribute__((ext_vector_type(4))) float f32x4;
typedef unsigned short u16;

#define DIM 1024
#define NH 16
#define HD 64
#define NB 8
#define L 512
#define ML (NB * L)  // 4096

__device__ __forceinline__ u16 f2bf(float f) {
  union { float f; unsigned int u; } x; x.f = f;
  unsigned int r = x.u + 0x7FFFu + ((x.u >> 16) & 1u);
  return (u16)(r >> 16);
}

// ---------------- f32 -> bf16 bulk convert (8 elems/thread) ----------------
__global__ __launch_bounds__(256) void cvt_bf16(const float* __restrict__ in,
                                                u16* __restrict__ out, int n8) {
  const int i = blockIdx.x * 256 + threadIdx.x;
  if (i >= n8) return;
  const float4 v0 = reinterpret_cast<const float4*>(in)[2 * i];
  const float4 v1 = reinterpret_cast<const float4*>(in)[2 * i + 1];
  ushort8 o;
  o[0] = f2bf(v0.x); o[1] = f2bf(v0.y); o[2] = f2bf(v0.z); o[3] = f2bf(v0.w);
  o[4] = f2bf(v1.x); o[5] = f2bf(v1.y); o[6] = f2bf(v1.z); o[7] = f2bf(v1.w);
  reinterpret_cast<ushort8*>(out)[i] = o;
}

// ---------------- GEMM: C[m,n] = sum_k A[m,k]*B[n,k] + bias[n] ----------------
// A: MxK bf16 row-major, B: NxK bf16 row-major (nn.Linear weight), 128x128 tile,
// 4 waves (2x2), each wave 64x64 = 4x4 frags of 16x16x32.
template <bool OUT_F32>
__global__ __launch_bounds__(256) void gemm_bt(
    const u16* __restrict__ A, const u16* __restrict__ Bw,
    const float* __restrict__ bias, void* __restrict__ Cp,
    int M, int N, int K) {
  __shared__ __align__(16) u16 As[128][40];  // +8 pad keeps 16B align, 2-way banks
  __shared__ __align__(16) u16 Bs[128][40];
  const int tid = threadIdx.x;
  const int lane = tid & 63;
  const int w = tid >> 6;
  const int wm = (w >> 1) * 64;
  const int wn = (w & 1) * 64;
  const int ll = lane & 15;
  const int lg = lane >> 4;
  const int bm = blockIdx.y * 128;
  const int bn = blockIdx.x * 128;

  f32x4 acc[4][4];
#pragma unroll
  for (int m = 0; m < 4; ++m)
#pragma unroll
    for (int n = 0; n < 4; ++n) acc[m][n] = (f32x4){0.f, 0.f, 0.f, 0.f};

  const int r0 = tid >> 2;
  const int c0 = (tid & 3) * 8;

  for (int kt = 0; kt < K; kt += 32) {
    *reinterpret_cast<ushort8*>(&As[r0][c0]) =
        *reinterpret_cast<const ushort8*>(A + (size_t)(bm + r0) * K + kt + c0);
    *reinterpret_cast<ushort8*>(&As[r0 + 64][c0]) =
        *reinterpret_cast<const ushort8*>(A + (size_t)(bm + r0 + 64) * K + kt + c0);
    *reinterpret_cast<ushort8*>(&Bs[r0][c0]) =
        *reinterpret_cast<const ushort8*>(Bw + (size_t)(bn + r0) * K + kt + c0);
    *reinterpret_cast<ushort8*>(&Bs[r0 + 64][c0]) =
        *reinterpret_cast<const ushort8*>(Bw + (size_t)(bn + r0 + 64) * K + kt + c0);
    __syncthreads();
    short8 af[4], bf[4];
#pragma unroll
    for (int m = 0; m < 4; ++m)
      af[m] = *reinterpret_cast<const short8*>(&As[wm + m * 16 + ll][lg * 8]);
#pragma unroll
    for (int n = 0; n < 4; ++n)
      bf[n] = *reinterpret_cast<const short8*>(&Bs[wn + n * 16 + ll][lg * 8]);
#pragma unroll
    for (int m = 0; m < 4; ++m)
#pragma unroll
      for (int n = 0; n < 4; ++n)
        acc[m][n] = __builtin_amdgcn_mfma_f32_16x16x32_bf16(af[m], bf[n], acc[m][n], 0, 0, 0);
    __syncthreads();
  }

#pragma unroll
  for (int m = 0; m < 4; ++m) {
#pragma unroll
    for (int n = 0; n < 4; ++n) {
#pragma unroll
      for (int r = 0; r < 4; ++r) {
        const int row = bm + wm + m * 16 + lg * 4 + r;  // D: row=(lane>>4)*4+reg
        const int col = bn + wn + n * 16 + ll;          //    col=lane&15
        const float v = acc[m][n][r] + bias[col];
        if constexpr (OUT_F32)
          reinterpret_cast<float*>(Cp)[(size_t)row * N + col] = v;
        else
          reinterpret_cast<u16*>(Cp)[(size_t)row * N + col] = f2bf(v);
      }
    }
  }
}

// ---------------- V transpose: vt[b,h,d,j] = v[b,j,h*64+d] ----------------
__global__ __launch_bounds__(256) void transpose_v(const u16* __restrict__ v,
                                                   u16* __restrict__ vt) {
  __shared__ u16 T[64][65];
  const int jt = blockIdx.x, h = blockIdx.y, b = blockIdx.z;
  const int tid = threadIdx.x;
#pragma unroll
  for (int rep = 0; rep < 16; ++rep) {
    const int idx = rep * 256 + tid;
    const int jr = idx >> 6, d = idx & 63;
    T[jr][d] = v[(size_t)(b * L + jt * 64 + jr) * DIM + h * HD + d];
  }
  __syncthreads();
#pragma unroll
  for (int rep = 0; rep < 16; ++rep) {
    const int idx = rep * 256 + tid;
    const int dr = idx >> 6, j = idx & 63;
    vt[(size_t)((b * NH + h) * HD + dr) * L + jt * 64 + j] = T[j][dr];
  }
}

// ---------------- a1u[b,h,i,q] = sum_p atc1[b,i,p] * U[h,p,q] ----------------
__global__ __launch_bounds__(256) void a1u_kernel(const float* __restrict__ atc1,
                                                  const float* __restrict__ U,
                                                  float* __restrict__ a1u) {
  const int idx = blockIdx.x * 256 + threadIdx.x;
  if (idx >= NB * NH * L * 5) return;
  const int q = idx % 5;
  const int i = (idx / 5) & (L - 1);
  const int h = (idx / (5 * L)) & (NH - 1);
  const int b = idx / (5 * L * NH);
  float s = 0.f;
#pragma unroll
  for (int p = 0; p < 5; ++p)
    s += atc1[(size_t)(b * L + i) * 5 + p] * U[(h * 5 + p) * 5 + q];
  a1u[idx] = s;
}

// ---------------- fused dual-softmax attention ----------------
// grid (L/32, NH, NB), 128 threads = 2 waves; wave owns 16 q-rows, full 512-col
// score rows in LDS (XOR-chunk swizzle breaks the row-major bank conflict).
__device__ __forceinline__ int swz(int row, int col) {
  return (col & 3) | (((col >> 2) ^ (row & 7)) << 2);
}

__global__ __launch_bounds__(128) void attn_kernel(
    const u16* __restrict__ qb, const u16* __restrict__ kb,
    const u16* __restrict__ vt, const float* __restrict__ a1u,
    const float* __restrict__ atc2, const float* __restrict__ mixp,
    u16* __restrict__ attb) {
  __shared__ __align__(16) float S[2][16][512];  // 64 KiB, one 16x512 row-block/wave
  const int tid = threadIdx.x;
  const int wv = tid >> 6;
  const int lane = tid & 63;
  const int lg = lane >> 4;
  const int ll = lane & 15;
  const int b = blockIdx.z, h = blockIdx.y;
  const int i0 = blockIdx.x * 32 + wv * 16;
  float(*Sw)[512] = S[wv];

  const float ratio = (tanhf(mixp[0]) + 1.0f) * 0.5f;

  // Q fragments: rows i0+ll, d = lg*8+e (+32 for second k-step)
  const u16* qp = qb + (size_t)(b * L + i0 + ll) * DIM + h * HD + lg * 8;
  const short8 aq0 = *reinterpret_cast<const short8*>(qp);
  const short8 aq1 = *reinterpret_cast<const short8*>(qp + 32);

  f32x4 O[4], Ofin[4];
  float lrs[4], lrb[4];

  auto softmax_rows = [&](float* lr) {
#pragma unroll
    for (int i = 0; i < 16; ++i) {
      float v[8];
      float mx = -1e30f;
#pragma unroll
      for (int t = 0; t < 8; ++t) {
        v[t] = Sw[i][swz(i, lane + 64 * t)];
        mx = fmaxf(mx, v[t]);
      }
#pragma unroll
      for (int off = 32; off > 0; off >>= 1) mx = fmaxf(mx, __shfl_xor(mx, off));
      float sum = 0.f;
#pragma unroll
      for (int t = 0; t < 8; ++t) {
        const float e = __expf(v[t] - mx);
        sum += e;
        Sw[i][swz(i, lane + 64 * t)] = e;  // unnormalized P back in place
      }
#pragma unroll
      for (int off = 32; off > 0; off >>= 1) sum += __shfl_xor(sum, off);
      if (lg == (i >> 2)) lr[i & 3] = sum;  // i unrolled -> static index
    }
  };

  auto pv = [&]() {
#pragma unroll
    for (int dt = 0; dt < 4; ++dt) O[dt] = (f32x4){0.f, 0.f, 0.f, 0.f};
    const float* prow = Sw[ll];
    const u16* vbase = vt + (size_t)((b * NH + h) * HD) * L;
#pragma unroll 2
    for (int kk = 0; kk < 16; ++kk) {
      const int cc = kk * 8 + lg * 2;  // float4-chunk index of k-range start
      const float4 p0 = *reinterpret_cast<const float4*>(prow + ((cc ^ (ll & 7)) << 2));
      const float4 p1 = *reinterpret_cast<const float4*>(prow + (((cc + 1) ^ (ll & 7)) << 2));
      short8 pa;
      pa[0] = (short)f2bf(p0.x); pa[1] = (short)f2bf(p0.y);
      pa[2] = (short)f2bf(p0.z); pa[3] = (short)f2bf(p0.w);
      pa[4] = (short)f2bf(p1.x); pa[5] = (short)f2bf(p1.y);
      pa[6] = (short)f2bf(p1.z); pa[7] = (short)f2bf(p1.w);
#pragma unroll
      for (int dt = 0; dt < 4; ++dt) {
        const short8 bv = *reinterpret_cast<const short8*>(
            vbase + (size_t)(dt * 16 + ll) * L + kk * 32 + lg * 8);
        O[dt] = __builtin_amdgcn_mfma_f32_16x16x32_bf16(pa, bv, O[dt], 0, 0, 0);
      }
    }
  };

  // ===== branch 1: standard scores S = QK^T / 8 =====
#pragma unroll 2
  for (int jt = 0; jt < 32; ++jt) {
    const u16* kp = kb + (size_t)(b * L + jt * 16 + ll) * DIM + h * HD + lg * 8;
    const short8 bk0 = *reinterpret_cast<const short8*>(kp);
    const short8 bk1 = *reinterpret_cast<const short8*>(kp + 32);
    f32x4 s = (f32x4){0.f, 0.f, 0.f, 0.f};
    s = __builtin_amdgcn_mfma_f32_16x16x32_bf16(aq0, bk0, s, 0, 0, 0);
    s = __builtin_amdgcn_mfma_f32_16x16x32_bf16(aq1, bk1, s, 0, 0, 0);
    const int col = jt * 16 + ll;
#pragma unroll
    for (int r = 0; r < 4; ++r) {
      const int row = lg * 4 + r;
      Sw[row][swz(row, col)] = s[r] * 0.125f;
    }
  }
  __syncthreads();
  softmax_rows(lrs);
  __syncthreads();
  pv();
#pragma unroll
  for (int dt = 0; dt < 4; ++dt)
#pragma unroll
    for (int r = 0; r < 4; ++r) Ofin[dt][r] = (1.0f - ratio) * O[dt][r] / lrs[r];
  __syncthreads();

  // ===== branch 2: Atchley scores S = a1u . atc2 =====
  {
    const float* aubase = a1u + (size_t)((b * NH + h) * L + i0) * 5;
#pragma unroll 2
    for (int t = 0; t < 8; ++t) {
      const int j = lane + 64 * t;
      const float* c2 = atc2 + (size_t)(b * L + j) * 5;
      const float c20 = c2[0], c21 = c2[1], c22 = c2[2], c23 = c2[3], c24 = c2[4];
#pragma unroll
      for (int i = 0; i < 16; ++i) {
        const float* au = aubase + i * 5;
        Sw[i][swz(i, j)] =
            au[0] * c20 + au[1] * c21 + au[2] * c22 + au[3] * c23 + au[4] * c24;
      }
    }
  }
  __syncthreads();
  softmax_rows(lrb);
  __syncthreads();
  pv();
#pragma unroll
  for (int dt = 0; dt < 4; ++dt)
#pragma unroll
    for (int r = 0; r < 4; ++r) Ofin[dt][r] += ratio * O[dt][r] / lrb[r];

#pragma unroll
  for (int dt = 0; dt < 4; ++dt)
#pragma unroll
    for (int r = 0; r < 4; ++r)
      attb[(size_t)(b * L + i0 + lg * 4 + r) * DIM + h * HD + dt * 16 + ll] =
          f2bf(Ofin[dt][r]);
}

// ---------------- launcher ----------------
extern "C" void kernel_launch(void* const* d_in, const int* in_sizes, int n_in,
                              void* d_out, int out_size, void* d_ws, size_t ws_size,
                              hipStream_t stream) {
  (void)in_sizes; (void)n_in; (void)out_size; (void)ws_size;
  const float* seq1 = (const float*)d_in[0];
  const float* seq2 = (const float*)d_in[1];
  const float* atc1 = (const float*)d_in[2];
  const float* atc2 = (const float*)d_in[3];
  const float* Wq = (const float*)d_in[4];
  const float* bq = (const float*)d_in[5];
  const float* Wk = (const float*)d_in[6];
  const float* bk = (const float*)d_in[7];
  const float* Wv = (const float*)d_in[8];
  const float* bv = (const float*)d_in[9];
  const float* Wo = (const float*)d_in[10];
  const float* bo = (const float*)d_in[11];
  const float* U = (const float*)d_in[12];
  const float* mixp = (const float*)d_in[13];

  char* ws = (char*)d_ws;
  const size_t SEQB = (size_t)ML * DIM * sizeof(u16);  // 8 MiB
  const size_t WB = (size_t)DIM * DIM * sizeof(u16);   // 2 MiB
  size_t o = 0;
  u16* s1b = (u16*)(ws + o); o += SEQB;
  u16* s2b = (u16*)(ws + o); o += SEQB;
  u16* wqb = (u16*)(ws + o); o += WB;
  u16* wkb = (u16*)(ws + o); o += WB;
  u16* wvb = (u16*)(ws + o); o += WB;
  u16* wob = (u16*)(ws + o); o += WB;
  u16* qb  = (u16*)(ws + o); o += SEQB;
  u16* kb  = (u16*)(ws + o); o += SEQB;
  u16* vb  = (u16*)(ws + o); o += SEQB;
  u16* vtb = (u16*)(ws + o); o += SEQB;
  u16* attb = (u16*)(ws + o); o += SEQB;
  float* a1u = (float*)(ws + o); o += (size_t)NB * NH * L * 5 * sizeof(float);

  const int seq_n8 = ML * DIM / 8;
  const int w_n8 = DIM * DIM / 8;
  cvt_bf16<<<(seq_n8 + 255) / 256, 256, 0, stream>>>(seq1, s1b, seq_n8);
  cvt_bf16<<<(seq_n8 + 255) / 256, 256, 0, stream>>>(seq2, s2b, seq_n8);
  cvt_bf16<<<(w_n8 + 255) / 256, 256, 0, stream>>>(Wq, wqb, w_n8);
  cvt_bf16<<<(w_n8 + 255) / 256, 256, 0, stream>>>(Wk, wkb, w_n8);
  cvt_bf16<<<(w_n8 + 255) / 256, 256, 0, stream>>>(Wv, wvb, w_n8);
  cvt_bf16<<<(w_n8 + 255) / 256, 256, 0, stream>>>(Wo, wob, w_n8);

  const dim3 gg(DIM / 128, ML / 128);  // (8, 32)
  gemm_bt<false><<<gg, 256, 0, stream>>>(s1b, wqb, bq, qb, ML, DIM, DIM);
  gemm_bt<false><<<gg, 256, 0, stream>>>(s2b, wkb, bk, kb, ML, DIM, DIM);
  gemm_bt<false><<<gg, 256, 0, stream>>>(s2b, wvb, bv, vb, ML, DIM, DIM);

  transpose_v<<<dim3(L / 64, NH, NB), 256, 0, stream>>>(vb, vtb);
  a1u_kernel<<<(NB * NH * L * 5 + 255) / 256, 256, 0, stream>>>(atc1, U, a1u);

  attn_kernel<<<dim3(L / 32, NH, NB), 128, 0, stream>>>(qb, kb, vtb, a1u, atc2,
                                                        mixp, attb);

  gemm_bt<true><<<gg, 256, 0, stream>>>(attb, wob, bo, (float*)d_out, ML, DIM, DIM);
}

// Round 2
// 265.479 us; speedup vs baseline: 1.4481x; 1.4481x over previous
//
#include <hip/hip_runtime.h>

typedef __attribute__((ext_vector_type(8))) short short8;
typedef __attribute__((ext_vector_type(8))) unsigned short ushort8;
typedef __attribute__((ext_vector_type(4))) float f32x4;
typedef unsigned short u16;

#define DIM 1024
#define NH 16
#define HD 64
#define NB 8
#define L 512
#define ML (NB * L)  // 4096

__device__ __forceinline__ u16 f2bf(float f) {
  union { float f; unsigned int u; } x; x.f = f;
  unsigned int r = x.u + 0x7FFFu + ((x.u >> 16) & 1u);
  return (u16)(r >> 16);
}

// async global -> LDS, 16 B per lane; lds base must be wave-uniform.
__device__ __forceinline__ void gld16(u16* lds, const u16* g) {
  __builtin_amdgcn_global_load_lds(
      (__attribute__((address_space(1))) void*)g,
      (__attribute__((address_space(3))) void*)lds, 16, 0, 0);
}

// ---------------- all f32 -> bf16 conversions in one launch ----------------
__global__ __launch_bounds__(256) void cvt_all(
    const float* __restrict__ s1, const float* __restrict__ s2,
    const float* __restrict__ wq, const float* __restrict__ wk,
    const float* __restrict__ wv, const float* __restrict__ wo,
    u16* __restrict__ o1, u16* __restrict__ o2, u16* __restrict__ oq,
    u16* __restrict__ ok, u16* __restrict__ ov, u16* __restrict__ oo) {
  const int blk = blockIdx.x;
  const float* src; u16* dst; int rel;
  if (blk < 2048)       { src = s1; dst = o1; rel = blk; }
  else if (blk < 4096)  { src = s2; dst = o2; rel = blk - 2048; }
  else if (blk < 4608)  { src = wq; dst = oq; rel = blk - 4096; }
  else if (blk < 5120)  { src = wk; dst = ok; rel = blk - 4608; }
  else if (blk < 5632)  { src = wv; dst = ov; rel = blk - 5120; }
  else                  { src = wo; dst = oo; rel = blk - 5632; }
  const int i = rel * 256 + threadIdx.x;
  const float4 v0 = reinterpret_cast<const float4*>(src)[2 * i];
  const float4 v1 = reinterpret_cast<const float4*>(src)[2 * i + 1];
  ushort8 o;
  o[0] = f2bf(v0.x); o[1] = f2bf(v0.y); o[2] = f2bf(v0.z); o[3] = f2bf(v0.w);
  o[4] = f2bf(v1.x); o[5] = f2bf(v1.y); o[6] = f2bf(v1.z); o[7] = f2bf(v1.w);
  reinterpret_cast<ushort8*>(dst)[i] = o;
}

// ---------------- GEMM (m97 structure): C[m,n] = sum_k A[m,k]*B[n,k] + bias ----------------
// BM=128, BK=32, global_load_lds width-16 staging, linear LDS, 2-barrier loop.
template <int BN, bool OUT_F32, bool KV>
__global__ __launch_bounds__(256) void gemm_lds(
    const u16* __restrict__ A, const u16* __restrict__ Bw,
    const float* __restrict__ b0, const float* __restrict__ b1,
    void* __restrict__ Cp, int M, int N, int K) {
  __shared__ __align__(16) u16 As[128 * 32];
  __shared__ __align__(16) u16 Bs[BN * 32];
  const int tid = threadIdx.x;
  const int lane = tid & 63;
  const int w = tid >> 6;
  const int ll = lane & 15, lg = lane >> 4;
  const int wm = (w >> 1) * 64;
  const int wn = (w & 1) * (BN / 2);
  constexpr int NF = BN / 32;
  const int bm = blockIdx.y * 128;
  const int bn = blockIdx.x * BN;

  f32x4 acc[4][NF];
#pragma unroll
  for (int m = 0; m < 4; ++m)
#pragma unroll
    for (int n = 0; n < NF; ++n) acc[m][n] = (f32x4){0.f, 0.f, 0.f, 0.f};

  for (int kt = 0; kt < K; kt += 32) {
#pragma unroll
    for (int it = 0; it < 2; ++it) {
      const int slot = it * 256 + tid;
      gld16(As + (it * 256 + w * 64) * 8,
            A + (size_t)(bm + (slot >> 2)) * K + kt + (slot & 3) * 8);
    }
#pragma unroll
    for (int it = 0; it < BN / 64; ++it) {
      const int slot = it * 256 + tid;
      gld16(Bs + (it * 256 + w * 64) * 8,
            Bw + (size_t)(bn + (slot >> 2)) * K + kt + (slot & 3) * 8);
    }
    __syncthreads();
    short8 af[4], bf[NF];
#pragma unroll
    for (int m = 0; m < 4; ++m)
      af[m] = *reinterpret_cast<const short8*>(&As[(wm + m * 16 + ll) * 32 + lg * 8]);
#pragma unroll
    for (int n = 0; n < NF; ++n)
      bf[n] = *reinterpret_cast<const short8*>(&Bs[(wn + n * 16 + ll) * 32 + lg * 8]);
#pragma unroll
    for (int m = 0; m < 4; ++m)
#pragma unroll
      for (int n = 0; n < NF; ++n)
        acc[m][n] = __builtin_amdgcn_mfma_f32_16x16x32_bf16(af[m], bf[n], acc[m][n], 0, 0, 0);
    __syncthreads();
  }

#pragma unroll
  for (int m = 0; m < 4; ++m) {
#pragma unroll
    for (int n = 0; n < NF; ++n) {
#pragma unroll
      for (int r = 0; r < 4; ++r) {
        const int row = bm + wm + m * 16 + lg * 4 + r;  // D: row=(lane>>4)*4+reg
        const int col = bn + wn + n * 16 + ll;          //    col=lane&15
        float bb;
        if constexpr (KV) bb = (col < DIM) ? b0[col] : b1[col - DIM];
        else bb = b0[col];
        const float v = acc[m][n][r] + bb;
        if constexpr (OUT_F32)
          reinterpret_cast<float*>(Cp)[(size_t)row * N + col] = v;
        else
          reinterpret_cast<u16*>(Cp)[(size_t)row * N + col] = f2bf(v);
      }
    }
  }
}

// ---------------- V transpose from fused KV buffer: vt[b,h,d,j] = kv[b,j,1024+h*64+d] ----------------
__global__ __launch_bounds__(256) void transpose_v(const u16* __restrict__ kvb,
                                                   u16* __restrict__ vt) {
  __shared__ u16 T[64][65];
  const int jt = blockIdx.x, h = blockIdx.y, bb = blockIdx.z;
  const int tid = threadIdx.x;
#pragma unroll
  for (int rep = 0; rep < 16; ++rep) {
    const int idx = rep * 256 + tid;
    const int jr = idx >> 6, d = idx & 63;
    T[jr][d] = kvb[(size_t)(bb * L + jt * 64 + jr) * 2048 + DIM + h * HD + d];
  }
  __syncthreads();
#pragma unroll
  for (int rep = 0; rep < 16; ++rep) {
    const int idx = rep * 256 + tid;
    const int dr = idx >> 6, j = idx & 63;
    vt[(size_t)((bb * NH + h) * HD + dr) * L + jt * 64 + j] = T[j][dr];
  }
}

// ---------------- a1u[b,h,i,q] = sum_p atc1[b,i,p] * U[h,p,q] ----------------
__global__ __launch_bounds__(256) void a1u_kernel(const float* __restrict__ atc1,
                                                  const float* __restrict__ U,
                                                  float* __restrict__ a1u) {
  const int idx = blockIdx.x * 256 + threadIdx.x;
  if (idx >= NB * NH * L * 5) return;
  const int q = idx % 5;
  const int i = (idx / 5) & (L - 1);
  const int h = (idx / (5 * L)) & (NH - 1);
  const int b = idx / (5 * L * NH);
  float s = 0.f;
#pragma unroll
  for (int p = 0; p < 5; ++p)
    s += atc1[(size_t)(b * L + i) * 5 + p] * U[(h * 5 + p) * 5 + q];
  a1u[idx] = s;
}

// ---------------- fused dual-softmax attention, merged-P single PV ----------------
// 1D grid 4096 (XCD-chunked: each XCD owns 16 consecutive (b,h) panels), 256 thr
// = 4 waves per 16 q-rows. LDS: one 16x512 f32 score buffer (padded rows).
__global__ __launch_bounds__(256, 4) void attn2(
    const u16* __restrict__ qb, const u16* __restrict__ kvb,
    const u16* __restrict__ vt, const float* __restrict__ a1u,
    const float* __restrict__ atc2, const float* __restrict__ mixp,
    u16* __restrict__ attb) {
  __shared__ __align__(16) float S[16][516];
  const int tid = threadIdx.x;
  const int wv = tid >> 6;
  const int lane = tid & 63;
  const int ll = lane & 15, lg = lane >> 4;
  const int bid = blockIdx.x;
  const int slot = bid >> 3;
  const int bh = (bid & 7) * 16 + (slot >> 5);  // 16 (b,h) panels per XCD
  const int it = slot & 31;
  const int b = bh >> 4, h = bh & 15;
  const int i0 = it * 16;

  const float ratio = (tanhf(mixp[0]) + 1.0f) * 0.5f;

  const u16* qp = qb + (size_t)(b * L + i0 + ll) * DIM + h * HD + lg * 8;
  const short8 aq0 = *reinterpret_cast<const short8*>(qp);
  const short8 aq1 = *reinterpret_cast<const short8*>(qp + 32);

  // ---- bio scores fully in registers: rows wv*4+ri, cols lane+64t ----
  float au[4][5];
#pragma unroll
  for (int ri = 0; ri < 4; ++ri) {
    const float* ap = a1u + (size_t)((b * NH + h) * L + i0 + wv * 4 + ri) * 5;
#pragma unroll
    for (int p = 0; p < 5; ++p) au[ri][p] = ap[p];
  }
  float bs[4][8];
#pragma unroll
  for (int t = 0; t < 8; ++t) {
    const int j = lane + 64 * t;
    const float* c2 = atc2 + (size_t)(b * L + j) * 5;
    const float c0 = c2[0], c1 = c2[1], cc2 = c2[2], c3 = c2[3], c4 = c2[4];
#pragma unroll
    for (int ri = 0; ri < 4; ++ri)
      bs[ri][t] = au[ri][0] * c0 + au[ri][1] * c1 + au[ri][2] * cc2 +
                  au[ri][3] * c3 + au[ri][4] * c4;
  }

  // ---- std scores: wave wv computes cols [wv*128, wv*128+128) ----
#pragma unroll 2
  for (int jt = 0; jt < 8; ++jt) {
    const int jj = wv * 8 + jt;
    const u16* kp = kvb + (size_t)(b * L + jj * 16 + ll) * 2048 + h * HD + lg * 8;
    const short8 k0 = *reinterpret_cast<const short8*>(kp);
    const short8 k1 = *reinterpret_cast<const short8*>(kp + 32);
    f32x4 s = (f32x4){0.f, 0.f, 0.f, 0.f};
    s = __builtin_amdgcn_mfma_f32_16x16x32_bf16(aq0, k0, s, 0, 0, 0);
    s = __builtin_amdgcn_mfma_f32_16x16x32_bf16(aq1, k1, s, 0, 0, 0);
#pragma unroll
    for (int r = 0; r < 4; ++r) S[lg * 4 + r][jj * 16 + ll] = s[r] * 0.125f;
  }
  __syncthreads();

  // ---- dual softmax + merge: wave wv owns rows wv*4..wv*4+3 ----
#pragma unroll
  for (int ri = 0; ri < 4; ++ri) {
    const int i = wv * 4 + ri;
    float v1[8];
    float m1 = -1e30f;
#pragma unroll
    for (int t = 0; t < 8; ++t) { v1[t] = S[i][lane + 64 * t]; m1 = fmaxf(m1, v1[t]); }
#pragma unroll
    for (int off = 32; off > 0; off >>= 1) m1 = fmaxf(m1, __shfl_xor(m1, off));
    float e1[8];
    float l1 = 0.f;
#pragma unroll
    for (int t = 0; t < 8; ++t) { e1[t] = __expf(v1[t] - m1); l1 += e1[t]; }
#pragma unroll
    for (int off = 32; off > 0; off >>= 1) l1 += __shfl_xor(l1, off);
    float m2 = -1e30f;
#pragma unroll
    for (int t = 0; t < 8; ++t) m2 = fmaxf(m2, bs[ri][t]);
#pragma unroll
    for (int off = 32; off > 0; off >>= 1) m2 = fmaxf(m2, __shfl_xor(m2, off));
    float e2[8];
    float l2 = 0.f;
#pragma unroll
    for (int t = 0; t < 8; ++t) { e2[t] = __expf(bs[ri][t] - m2); l2 += e2[t]; }
#pragma unroll
    for (int off = 32; off > 0; off >>= 1) l2 += __shfl_xor(l2, off);
    const float sc1 = (1.f - ratio) / l1, sc2 = ratio / l2;
#pragma unroll
    for (int t = 0; t < 8; ++t) S[i][lane + 64 * t] = sc1 * e1[t] + sc2 * e2[t];
  }
  __syncthreads();

  // ---- single PV pass: wave wv owns d-block wv (16 cols) ----
  f32x4 O = (f32x4){0.f, 0.f, 0.f, 0.f};
  const u16* vbase = vt + ((size_t)(b * NH + h) * HD + wv * 16 + ll) * L;
#pragma unroll 4
  for (int kk = 0; kk < 16; ++kk) {
    const float* pr = &S[ll][kk * 32 + lg * 8];
    const float4 p0 = *reinterpret_cast<const float4*>(pr);
    const float4 p1 = *reinterpret_cast<const float4*>(pr + 4);
    short8 pa;
    pa[0] = (short)f2bf(p0.x); pa[1] = (short)f2bf(p0.y);
    pa[2] = (short)f2bf(p0.z); pa[3] = (short)f2bf(p0.w);
    pa[4] = (short)f2bf(p1.x); pa[5] = (short)f2bf(p1.y);
    pa[6] = (short)f2bf(p1.z); pa[7] = (short)f2bf(p1.w);
    const short8 bv = *reinterpret_cast<const short8*>(vbase + kk * 32 + lg * 8);
    O = __builtin_amdgcn_mfma_f32_16x16x32_bf16(pa, bv, O, 0, 0, 0);
  }
#pragma unroll
  for (int r = 0; r < 4; ++r)
    attb[(size_t)(b * L + i0 + lg * 4 + r) * DIM + h * HD + wv * 16 + ll] = f2bf(O[r]);
}

// ---------------- launcher ----------------
extern "C" void kernel_launch(void* const* d_in, const int* in_sizes, int n_in,
                              void* d_out, int out_size, void* d_ws, size_t ws_size,
                              hipStream_t stream) {
  (void)in_sizes; (void)n_in; (void)out_size; (void)ws_size;
  const float* seq1 = (const float*)d_in[0];
  const float* seq2 = (const float*)d_in[1];
  const float* atc1 = (const float*)d_in[2];
  const float* atc2 = (const float*)d_in[3];
  const float* Wq = (const float*)d_in[4];
  const float* bq = (const float*)d_in[5];
  const float* Wk = (const float*)d_in[6];
  const float* bk = (const float*)d_in[7];
  const float* Wv = (const float*)d_in[8];
  const float* bv = (const float*)d_in[9];
  const float* Wo = (const float*)d_in[10];
  const float* bo = (const float*)d_in[11];
  const float* U = (const float*)d_in[12];
  const float* mixp = (const float*)d_in[13];

  char* ws = (char*)d_ws;
  const size_t SEQB = (size_t)ML * DIM * sizeof(u16);   // 8 MiB
  const size_t WB = (size_t)DIM * DIM * sizeof(u16);    // 2 MiB
  size_t o = 0;
  u16* s1b = (u16*)(ws + o); o += SEQB;
  u16* s2b = (u16*)(ws + o); o += SEQB;
  u16* wqb = (u16*)(ws + o); o += WB;
  u16* wkvb = (u16*)(ws + o); o += 2 * WB;              // Wk ; Wv contiguous
  u16* wob = (u16*)(ws + o); o += WB;
  u16* qb = (u16*)(ws + o); o += SEQB;
  u16* kvb = (u16*)(ws + o); o += 2 * SEQB;             // [4096][2048] K|V
  u16* vtb = (u16*)(ws + o); o += SEQB;
  u16* attb = (u16*)(ws + o); o += SEQB;
  float* a1u = (float*)(ws + o); o += (size_t)NB * NH * L * 5 * sizeof(float);

  cvt_all<<<6144, 256, 0, stream>>>(seq1, seq2, Wq, Wk, Wv, Wo, s1b, s2b, wqb,
                                    wkvb, wkvb + (size_t)DIM * DIM, wob);

  gemm_lds<64, false, false><<<dim3(16, 32), 256, 0, stream>>>(
      s1b, wqb, bq, bq, qb, ML, DIM, DIM);
  gemm_lds<128, false, true><<<dim3(16, 32), 256, 0, stream>>>(
      s2b, wkvb, bk, bv, kvb, ML, 2048, DIM);

  transpose_v<<<dim3(L / 64, NH, NB), 256, 0, stream>>>(kvb, vtb);
  a1u_kernel<<<(NB * NH * L * 5 + 255) / 256, 256, 0, stream>>>(atc1, U, a1u);

  attn2<<<4096, 256, 0, stream>>>(qb, kvb, vtb, a1u, atc2, mixp, attb);

  gemm_lds<64, true, false><<<dim3(16, 32), 256, 0, stream>>>(
      attb, wob, bo, bo, (float*)d_out, ML, DIM, DIM);
}

// Round 5
// 259.023 us; speedup vs baseline: 1.4842x; 1.0249x over previous
//
#include <hip/hip_runtime.h>
#include <hip/hip_bf16.h>

typedef __attribute__((ext_vector_type(8))) short short8;
typedef __attribute__((ext_vector_type(8))) unsigned short ushort8;
typedef __attribute__((ext_vector_type(4))) float f32x4;
typedef unsigned short u16;

#define DIM 1024
#define NH 16
#define HD 64
#define NB 8
#define L 512
#define ML (NB * L)  // 4096

__device__ __forceinline__ u16 f2bf(float f) {
  union { float f; unsigned int u; } x; x.f = f;
  unsigned int r = x.u + 0x7FFFu + ((x.u >> 16) & 1u);
  return (u16)(r >> 16);
}

__device__ __forceinline__ unsigned int pkbf(float a, float b) {
  union { __hip_bfloat162 h; unsigned int u; } r;
  r.h = __float22bfloat162_rn(float2{a, b});  // compiler emits v_cvt_pk_bf16_f32
  return r.u;
}

// async global -> LDS, 16 B per lane; lds base must be wave-uniform.
__device__ __forceinline__ void gld16(u16* lds, const u16* g) {
  __builtin_amdgcn_global_load_lds(
      (__attribute__((address_space(1))) void*)g,
      (__attribute__((address_space(3))) void*)lds, 16, 0, 0);
}

// ---------------- all f32 -> bf16 conversions in one launch ----------------
__global__ __launch_bounds__(256) void cvt_all(
    const float* __restrict__ s1, const float* __restrict__ s2,
    const float* __restrict__ wq, const float* __restrict__ wk,
    const float* __restrict__ wv, const float* __restrict__ wo,
    u16* __restrict__ o1, u16* __restrict__ o2, u16* __restrict__ oq,
    u16* __restrict__ ok, u16* __restrict__ ov, u16* __restrict__ oo) {
  const int blk = blockIdx.x;
  const float* src; u16* dst; int rel;
  if (blk < 2048)       { src = s1; dst = o1; rel = blk; }
  else if (blk < 4096)  { src = s2; dst = o2; rel = blk - 2048; }
  else if (blk < 4608)  { src = wq; dst = oq; rel = blk - 4096; }
  else if (blk < 5120)  { src = wk; dst = ok; rel = blk - 4608; }
  else if (blk < 5632)  { src = wv; dst = ov; rel = blk - 5120; }
  else                  { src = wo; dst = oo; rel = blk - 5632; }
  const int i = rel * 256 + threadIdx.x;
  const float4 v0 = reinterpret_cast<const float4*>(src)[2 * i];
  const float4 v1 = reinterpret_cast<const float4*>(src)[2 * i + 1];
  ushort8 o;
  o[0] = f2bf(v0.x); o[1] = f2bf(v0.y); o[2] = f2bf(v0.z); o[3] = f2bf(v0.w);
  o[4] = f2bf(v1.x); o[5] = f2bf(v1.y); o[6] = f2bf(v1.z); o[7] = f2bf(v1.w);
  reinterpret_cast<ushort8*>(dst)[i] = o;
}

// ---------------- GEMM, double-buffered 2-phase: C = A·B^T + bias ----------------
// BM=128, BK=32. Stage tile t+1 BEFORE compute of tile t; one barrier per K-step.
template <int BN, bool OUT_F32, bool KV, int NT>
__global__ __launch_bounds__(256) void gemm_db(
    const u16* __restrict__ A, const u16* __restrict__ Bw,
    const float* __restrict__ b0, const float* __restrict__ b1,
    void* __restrict__ Cp, int N, int K) {
  __shared__ __align__(16) u16 As[2][128 * 32];
  __shared__ __align__(16) u16 Bs[2][BN * 32];
  const int tid = threadIdx.x;
  const int lane = tid & 63;
  const int w = tid >> 6;
  const int ll = lane & 15, lg = lane >> 4;
  const int wm = (w >> 1) * 64;
  const int wn = (w & 1) * (BN / 2);
  constexpr int NF = BN / 32;
  // XCD-chunked tile swizzle (grid % 8 == 0): each XCD gets contiguous bm rows
  const int bid = blockIdx.x;
  const int tile = (bid & 7) * (gridDim.x >> 3) + (bid >> 3);
  const int bm = (tile / NT) * 128;
  const int bn = (tile % NT) * BN;

  f32x4 acc[4][NF];
#pragma unroll
  for (int m = 0; m < 4; ++m)
#pragma unroll
    for (int n = 0; n < NF; ++n) acc[m][n] = (f32x4){0.f, 0.f, 0.f, 0.f};

  auto stage = [&](int bi, int kt) {
#pragma unroll
    for (int it = 0; it < 2; ++it) {
      const int slot = it * 256 + tid;
      gld16(&As[bi][(it * 256 + w * 64) * 8],
            A + (size_t)(bm + (slot >> 2)) * K + kt + (slot & 3) * 8);
    }
#pragma unroll
    for (int it = 0; it < BN / 64; ++it) {
      const int slot = it * 256 + tid;
      gld16(&Bs[bi][(it * 256 + w * 64) * 8],
            Bw + (size_t)(bn + (slot >> 2)) * K + kt + (slot & 3) * 8);
    }
  };

  stage(0, 0);
  __syncthreads();
  int cur = 0;
  for (int kt = 0; kt < K; kt += 32) {
    if (kt + 32 < K) stage(cur ^ 1, kt + 32);  // prefetch overlaps MFMA below
    short8 af[4], bf[NF];
#pragma unroll
    for (int m = 0; m < 4; ++m)
      af[m] = *reinterpret_cast<const short8*>(&As[cur][(wm + m * 16 + ll) * 32 + lg * 8]);
#pragma unroll
    for (int n = 0; n < NF; ++n)
      bf[n] = *reinterpret_cast<const short8*>(&Bs[cur][(wn + n * 16 + ll) * 32 + lg * 8]);
#pragma unroll
    for (int m = 0; m < 4; ++m)
#pragma unroll
      for (int n = 0; n < NF; ++n)
        acc[m][n] = __builtin_amdgcn_mfma_f32_16x16x32_bf16(af[m], bf[n], acc[m][n], 0, 0, 0);
    __syncthreads();  // drains prefetch vmcnt + lgkm; both buffers consistent
    cur ^= 1;
  }

#pragma unroll
  for (int m = 0; m < 4; ++m) {
#pragma unroll
    for (int n = 0; n < NF; ++n) {
#pragma unroll
      for (int r = 0; r < 4; ++r) {
        const int row = bm + wm + m * 16 + lg * 4 + r;  // D: row=(lane>>4)*4+reg
        const int col = bn + wn + n * 16 + ll;          //    col=lane&15
        float bb;
        if constexpr (KV) bb = (col < DIM) ? b0[col] : b1[col - DIM];
        else bb = b0[col];
        const float v = acc[m][n][r] + bb;
        if constexpr (OUT_F32)
          reinterpret_cast<float*>(Cp)[(size_t)row * N + col] = v;
        else
          reinterpret_cast<u16*>(Cp)[(size_t)row * N + col] = f2bf(v);
      }
    }
  }
}

// ---------------- V transpose from fused KV buffer: vt[b,h,d,j] = kv[b,j,1024+h*64+d] ----------------
__global__ __launch_bounds__(256) void transpose_v(const u16* __restrict__ kvb,
                                                   u16* __restrict__ vt) {
  __shared__ u16 T[64][65];
  const int jt = blockIdx.x, h = blockIdx.y, bb = blockIdx.z;
  const int tid = threadIdx.x;
#pragma unroll
  for (int rep = 0; rep < 16; ++rep) {
    const int idx = rep * 256 + tid;
    const int jr = idx >> 6, d = idx & 63;
    T[jr][d] = kvb[(size_t)(bb * L + jt * 64 + jr) * 2048 + DIM + h * HD + d];
  }
  __syncthreads();
#pragma unroll
  for (int rep = 0; rep < 16; ++rep) {
    const int idx = rep * 256 + tid;
    const int dr = idx >> 6, j = idx & 63;
    vt[(size_t)((bb * NH + h) * HD + dr) * L + jt * 64 + j] = T[j][dr];
  }
}

// ---------------- a1u[b,h,i,q] = sum_p atc1[b,i,p] * U[h,p,q] ----------------
__global__ __launch_bounds__(256) void a1u_kernel(const float* __restrict__ atc1,
                                                  const float* __restrict__ U,
                                                  float* __restrict__ a1u) {
  const int idx = blockIdx.x * 256 + threadIdx.x;
  if (idx >= NB * NH * L * 5) return;
  const int q = idx % 5;
  const int i = (idx / 5) & (L - 1);
  const int h = (idx / (5 * L)) & (NH - 1);
  const int b = idx / (5 * L * NH);
  float s = 0.f;
#pragma unroll
  for (int p = 0; p < 5; ++p)
    s += atc1[(size_t)(b * L + i) * 5 + p] * U[(h * 5 + p) * 5 + q];
  a1u[idx] = s;
}

// ---------------- fused dual-softmax attention v3 ----------------
// grid 4096 1D (XCD-chunked), 256 thr = 4 waves per 16 q-rows.
// LDS: 16x512 f32 scores (row-XOR chunk swizzle); merged P overwrites it as bf16.
// No max-subtraction (scores bounded |S|<~3); sum butterflies only, interleaved.
__global__ __launch_bounds__(256, 4) void attn3(
    const u16* __restrict__ qb, const u16* __restrict__ kvb,
    const u16* __restrict__ vt, const float* __restrict__ a1u,
    const float* __restrict__ atc2, const float* __restrict__ mixp,
    u16* __restrict__ attb) {
  __shared__ __align__(16) float Sf[16 * 512];  // 32 KB
  const int tid = threadIdx.x;
  const int wv = tid >> 6;
  const int lane = tid & 63;
  const int ll = lane & 15, lg = lane >> 4;
  const int bid = blockIdx.x;
  const int slot = bid >> 3;
  const int bh = (bid & 7) * 16 + (slot >> 5);  // 16 (b,h) panels per XCD
  const int it = slot & 31;
  const int b = bh >> 4, h = bh & 15;
  const int i0 = it * 16;

  const float ratio = (tanhf(mixp[0]) + 1.0f) * 0.5f;

  // ---- Q fragments ----
  const u16* qp = qb + (size_t)(b * L + i0 + ll) * DIM + h * HD + lg * 8;
  const short8 aq0 = *reinterpret_cast<const short8*>(qp);
  const short8 aq1 = *reinterpret_cast<const short8*>(qp + 32);

  // ---- bio scores upfront (atc2 regs freed after this block) ----
  // lane owns k-cols [4*lane, 4*lane+4) and [256+4*lane, +4)
  float bs[4][8];
  {
    float r2a[20], r2b[20];
    {
      const float4* pa = reinterpret_cast<const float4*>(atc2 + ((size_t)b * L + 4 * lane) * 5);
      const float4* pb = reinterpret_cast<const float4*>(atc2 + ((size_t)b * L + 256 + 4 * lane) * 5);
#pragma unroll
      for (int u = 0; u < 5; ++u) {
        const float4 ta = pa[u], tb = pb[u];
        r2a[4 * u] = ta.x; r2a[4 * u + 1] = ta.y; r2a[4 * u + 2] = ta.z; r2a[4 * u + 3] = ta.w;
        r2b[4 * u] = tb.x; r2b[4 * u + 1] = tb.y; r2b[4 * u + 2] = tb.z; r2b[4 * u + 3] = tb.w;
      }
    }
    const float* a1p = a1u + ((size_t)(b * NH + h) * L + i0 + wv * 4) * 5;  // uniform
    float a1v[20];
#pragma unroll
    for (int p = 0; p < 20; ++p) a1v[p] = a1p[p];
#pragma unroll
    for (int ri = 0; ri < 4; ++ri) {
#pragma unroll
      for (int j = 0; j < 4; ++j) {
        float sa = 0.f, sb = 0.f;
#pragma unroll
        for (int p = 0; p < 5; ++p) {
          sa += a1v[ri * 5 + p] * r2a[j * 5 + p];
          sb += a1v[ri * 5 + p] * r2b[j * 5 + p];
        }
        bs[ri][j] = sa; bs[ri][j + 4] = sb;
      }
    }
  }

  // ---- std scores: wave wv computes cols [wv*128, +128); row-XOR chunk store ----
#pragma unroll
  for (int jt8 = 0; jt8 < 8; ++jt8) {
    const int jj = wv * 8 + jt8;
    const u16* kp = kvb + (size_t)(b * L + jj * 16 + ll) * 2048 + h * HD + lg * 8;
    const short8 k0 = *reinterpret_cast<const short8*>(kp);
    const short8 k1 = *reinterpret_cast<const short8*>(kp + 32);
    f32x4 s = (f32x4){0.f, 0.f, 0.f, 0.f};
    s = __builtin_amdgcn_mfma_f32_16x16x32_bf16(aq0, k0, s, 0, 0, 0);
    s = __builtin_amdgcn_mfma_f32_16x16x32_bf16(aq1, k1, s, 0, 0, 0);
    const int cfb = jj * 4 + (ll >> 2);
#pragma unroll
    for (int r = 0; r < 4; ++r) {
      const int row = lg * 4 + r;
      Sf[row * 512 + (((cfb ^ (row & 7)) << 2) | (ll & 3))] = s[r] * 0.125f;
    }
  }
  __syncthreads();

  // ---- merged dual softmax: wave wv owns rows wv*4..+3; P overwrites Sf as bf16 ----
#pragma unroll
  for (int ri = 0; ri < 4; ++ri) {
    const int i = wv * 4 + ri;
    const int p1 = lane ^ (i & 7);  // stored position of natural chunk `lane`
    const float4 x1 = *reinterpret_cast<const float4*>(&Sf[i * 512 + (p1 << 2)]);
    const float4 x2 = *reinterpret_cast<const float4*>(&Sf[i * 512 + ((64 + p1) << 2)]);
    float e1[8], e2[8];
    e1[0] = __expf(x1.x); e1[1] = __expf(x1.y); e1[2] = __expf(x1.z); e1[3] = __expf(x1.w);
    e1[4] = __expf(x2.x); e1[5] = __expf(x2.y); e1[6] = __expf(x2.z); e1[7] = __expf(x2.w);
#pragma unroll
    for (int j = 0; j < 8; ++j) e2[j] = __expf(bs[ri][j]);
    float l1 = 0.f, l2 = 0.f;
#pragma unroll
    for (int j = 0; j < 8; ++j) { l1 += e1[j]; l2 += e2[j]; }
#pragma unroll
    for (int off = 32; off > 0; off >>= 1) {
      l1 += __shfl_xor(l1, off);
      l2 += __shfl_xor(l2, off);
    }
    const float sc1 = (1.f - ratio) / l1, sc2 = ratio / l2;
    float p[8];
#pragma unroll
    for (int j = 0; j < 8; ++j) p[j] = sc1 * e1[j] + sc2 * e2[j];
    // write merged P (bf16) in place, natural position; value depends on full
    // butterfly -> all row reads complete before any row write (same wave).
    char* rowb = reinterpret_cast<char*>(Sf) + i * 2048;
    uint2 w0; w0.x = pkbf(p[0], p[1]); w0.y = pkbf(p[2], p[3]);
    uint2 w1; w1.x = pkbf(p[4], p[5]); w1.y = pkbf(p[6], p[7]);
    *reinterpret_cast<uint2*>(rowb + 8 * lane) = w0;
    *reinterpret_cast<uint2*>(rowb + 512 + 8 * lane) = w1;
  }
  __syncthreads();

  // ---- single PV pass: wave wv owns d-block wv (16 cols) ----
  f32x4 O = (f32x4){0.f, 0.f, 0.f, 0.f};
  const u16* vbase = vt + ((size_t)(b * NH + h) * HD + wv * 16 + ll) * L;
  const char* Pb = reinterpret_cast<const char*>(Sf) + ll * 2048;
#pragma unroll
  for (int kk = 0; kk < 16; ++kk) {
    const short8 pa = *reinterpret_cast<const short8*>(Pb + kk * 64 + lg * 16);
    const short8 bv = *reinterpret_cast<const short8*>(vbase + kk * 32 + lg * 8);
    O = __builtin_amdgcn_mfma_f32_16x16x32_bf16(pa, bv, O, 0, 0, 0);
  }
#pragma unroll
  for (int r = 0; r < 4; ++r)
    attb[(size_t)(b * L + i0 + lg * 4 + r) * DIM + h * HD + wv * 16 + ll] = f2bf(O[r]);
}

// ---------------- launcher ----------------
extern "C" void kernel_launch(void* const* d_in, const int* in_sizes, int n_in,
                              void* d_out, int out_size, void* d_ws, size_t ws_size,
                              hipStream_t stream) {
  (void)in_sizes; (void)n_in; (void)out_size; (void)ws_size;
  const float* seq1 = (const float*)d_in[0];
  const float* seq2 = (const float*)d_in[1];
  const float* atc1 = (const float*)d_in[2];
  const float* atc2 = (const float*)d_in[3];
  const float* Wq = (const float*)d_in[4];
  const float* bq = (const float*)d_in[5];
  const float* Wk = (const float*)d_in[6];
  const float* bk = (const float*)d_in[7];
  const float* Wv = (const float*)d_in[8];
  const float* bv = (const float*)d_in[9];
  const float* Wo = (const float*)d_in[10];
  const float* bo = (const float*)d_in[11];
  const float* U = (const float*)d_in[12];
  const float* mixp = (const float*)d_in[13];

  char* ws = (char*)d_ws;
  const size_t SEQB = (size_t)ML * DIM * sizeof(u16);   // 8 MiB
  const size_t WB = (size_t)DIM * DIM * sizeof(u16);    // 2 MiB
  size_t o = 0;
  u16* s1b = (u16*)(ws + o); o += SEQB;
  u16* s2b = (u16*)(ws + o); o += SEQB;
  u16* wqb = (u16*)(ws + o); o += WB;
  u16* wkvb = (u16*)(ws + o); o += 2 * WB;              // Wk ; Wv contiguous
  u16* wob = (u16*)(ws + o); o += WB;
  u16* qb = (u16*)(ws + o); o += SEQB;
  u16* kvb = (u16*)(ws + o); o += 2 * SEQB;             // [4096][2048] K|V
  u16* vtb = (u16*)(ws + o); o += SEQB;
  u16* attb = (u16*)(ws + o); o += SEQB;
  float* a1u = (float*)(ws + o); o += (size_t)NB * NH * L * 5 * sizeof(float);

  cvt_all<<<6144, 256, 0, stream>>>(seq1, seq2, Wq, Wk, Wv, Wo, s1b, s2b, wqb,
                                    wkvb, wkvb + (size_t)DIM * DIM, wob);

  gemm_db<64, false, false, 16><<<512, 256, 0, stream>>>(s1b, wqb, bq, bq, qb, DIM, DIM);
  gemm_db<128, false, true, 16><<<512, 256, 0, stream>>>(s2b, wkvb, bk, bv, kvb, 2048, DIM);

  transpose_v<<<dim3(L / 64, NH, NB), 256, 0, stream>>>(kvb, vtb);
  a1u_kernel<<<(NB * NH * L * 5 + 255) / 256, 256, 0, stream>>>(atc1, U, a1u);

  attn3<<<4096, 256, 0, stream>>>(qb, kvb, vtb, a1u, atc2, mixp, attb);

  gemm_db<64, true, false, 16><<<512, 256, 0, stream>>>(attb, wob, bo, bo, (float*)d_out, DIM, DIM);
}

// Round 10
// 258.085 us; speedup vs baseline: 1.4896x; 1.0036x over previous
//
#include <hip/hip_runtime.h>
#include <hip/hip_bf16.h>

typedef __attribute__((ext_vector_type(8))) short short8;
typedef __attribute__((ext_vector_type(8))) unsigned short ushort8;
typedef __attribute__((ext_vector_type(4))) float f32x4;
typedef unsigned short u16;

#define DIM 1024
#define NH 16
#define HD 64
#define NB 8
#define L 512
#define ML (NB * L)  // 4096

__device__ __forceinline__ u16 f2bf(float f) {
  union { float f; unsigned int u; } x; x.f = f;
  unsigned int r = x.u + 0x7FFFu + ((x.u >> 16) & 1u);
  return (u16)(r >> 16);
}

__device__ __forceinline__ unsigned int pkbf(float a, float b) {
  union { __hip_bfloat162 h; unsigned int u; } r;
  r.h = __float22bfloat162_rn(float2{a, b});  // v_cvt_pk_bf16_f32
  return r.u;
}

// async global -> LDS, 16 B per lane; lds base must be wave-uniform.
__device__ __forceinline__ void gld16(u16* lds, const u16* g) {
  __builtin_amdgcn_global_load_lds(
      (__attribute__((address_space(1))) void*)g,
      (__attribute__((address_space(3))) void*)lds, 16, 0, 0);
}

// ---------------- all f32 -> bf16 conversions in one launch ----------------
__global__ __launch_bounds__(256) void cvt_all(
    const float* __restrict__ s1, const float* __restrict__ s2,
    const float* __restrict__ wq, const float* __restrict__ wk,
    const float* __restrict__ wv, const float* __restrict__ wo,
    u16* __restrict__ o1, u16* __restrict__ o2, u16* __restrict__ oq,
    u16* __restrict__ ok, u16* __restrict__ ov, u16* __restrict__ oo) {
  const int blk = blockIdx.x;
  const float* src; u16* dst; int rel;
  if (blk < 2048)       { src = s1; dst = o1; rel = blk; }
  else if (blk < 4096)  { src = s2; dst = o2; rel = blk - 2048; }
  else if (blk < 4608)  { src = wq; dst = oq; rel = blk - 4096; }
  else if (blk < 5120)  { src = wk; dst = ok; rel = blk - 4608; }
  else if (blk < 5632)  { src = wv; dst = ov; rel = blk - 5120; }
  else                  { src = wo; dst = oo; rel = blk - 5632; }
  const int i = rel * 256 + threadIdx.x;
  const float4 v0 = reinterpret_cast<const float4*>(src)[2 * i];
  const float4 v1 = reinterpret_cast<const float4*>(src)[2 * i + 1];
  ushort8 o;
  o[0] = f2bf(v0.x); o[1] = f2bf(v0.y); o[2] = f2bf(v0.z); o[3] = f2bf(v0.w);
  o[4] = f2bf(v1.x); o[5] = f2bf(v1.y); o[6] = f2bf(v1.z); o[7] = f2bf(v1.w);
  reinterpret_cast<ushort8*>(dst)[i] = o;
}

// ---------------- GEMM, double-buffered, BK=64: C = A·B^T + bias ----------------
// Linear LDS dest (global_load_lds) + pre-swizzled GLOBAL source; ds_read uses
// the same chunk involution pc = c ^ (row&7)  -> bank-conflict-free at BK=64.
template <int BN, bool OUT_F32, bool KV, int NT>
__global__ __launch_bounds__(256) void gemm_db(
    const u16* __restrict__ A, const u16* __restrict__ Bw,
    const float* __restrict__ b0, const float* __restrict__ b1,
    void* __restrict__ Cp, int N, int K) {
  __shared__ __align__(16) u16 As[2][128 * 64];
  __shared__ __align__(16) u16 Bs[2][BN * 64];
  const int tid = threadIdx.x;
  const int lane = tid & 63;
  const int w = tid >> 6;
  const int ll = lane & 15, lg = lane >> 4;
  const int wm = (w >> 1) * 64;
  const int wn = (w & 1) * (BN / 2);
  constexpr int NF = BN / 32;
  // XCD-chunked tile swizzle (grid % 8 == 0)
  const int bid = blockIdx.x;
  const int tile = (bid & 7) * (gridDim.x >> 3) + (bid >> 3);
  const int bm = (tile / NT) * 128;
  const int bn = (tile % NT) * BN;

  f32x4 acc[4][NF];
#pragma unroll
  for (int m = 0; m < 4; ++m)
#pragma unroll
    for (int n = 0; n < NF; ++n) acc[m][n] = (f32x4){0.f, 0.f, 0.f, 0.f};

  auto stage = [&](int bi, int kt) {
#pragma unroll
    for (int it = 0; it < 4; ++it) {  // A: 128 rows x 64 cols = 4 x 256 x 16B
      const int slot = it * 256 + tid;
      const int row = slot >> 3, pch = slot & 7;
      gld16(&As[bi][(it * 256 + w * 64) * 8],
            A + (size_t)(bm + row) * K + kt + ((pch ^ (row & 7)) * 8));
    }
#pragma unroll
    for (int it = 0; it < BN / 32; ++it) {
      const int slot = it * 256 + tid;
      const int row = slot >> 3, pch = slot & 7;
      gld16(&Bs[bi][(it * 256 + w * 64) * 8],
            Bw + (size_t)(bn + row) * K + kt + ((pch ^ (row & 7)) * 8));
    }
  };

  stage(0, 0);
  __syncthreads();
  int cur = 0;
  for (int kt = 0; kt < K; kt += 64) {
    if (kt + 64 < K) stage(cur ^ 1, kt + 64);  // prefetch overlaps MFMA below
#pragma unroll
    for (int s = 0; s < 2; ++s) {
      short8 af[4], bf[NF];
#pragma unroll
      for (int m = 0; m < 4; ++m) {
        const int row = wm + m * 16 + ll;
        af[m] = *reinterpret_cast<const short8*>(
            &As[cur][row * 64 + (((s * 4 + lg) ^ (row & 7)) * 8)]);
      }
#pragma unroll
      for (int n = 0; n < NF; ++n) {
        const int row = wn + n * 16 + ll;
        bf[n] = *reinterpret_cast<const short8*>(
            &Bs[cur][row * 64 + (((s * 4 + lg) ^ (row & 7)) * 8)]);
      }
#pragma unroll
      for (int m = 0; m < 4; ++m)
#pragma unroll
        for (int n = 0; n < NF; ++n)
          acc[m][n] = __builtin_amdgcn_mfma_f32_16x16x32_bf16(af[m], bf[n], acc[m][n], 0, 0, 0);
    }
    __syncthreads();
    cur ^= 1;
  }

#pragma unroll
  for (int m = 0; m < 4; ++m) {
#pragma unroll
    for (int n = 0; n < NF; ++n) {
#pragma unroll
      for (int r = 0; r < 4; ++r) {
        const int row = bm + wm + m * 16 + lg * 4 + r;  // D: row=(lane>>4)*4+reg
        const int col = bn + wn + n * 16 + ll;          //    col=lane&15
        float bb;
        if constexpr (KV) bb = (col < DIM) ? b0[col] : b1[col - DIM];
        else bb = b0[col];
        const float v = acc[m][n][r] + bb;
        if constexpr (OUT_F32)
          reinterpret_cast<float*>(Cp)[(size_t)row * N + col] = v;
        else
          reinterpret_cast<u16*>(Cp)[(size_t)row * N + col] = f2bf(v);
      }
    }
  }
}

// ---------------- V transpose from fused KV buffer: vt[b,h,d,j] = kv[b,j,1024+h*64+d] ----------------
__global__ __launch_bounds__(256) void transpose_v(const u16* __restrict__ kvb,
                                                   u16* __restrict__ vt) {
  __shared__ u16 T[64][65];
  const int jt = blockIdx.x, h = blockIdx.y, bb = blockIdx.z;
  const int tid = threadIdx.x;
#pragma unroll
  for (int rep = 0; rep < 16; ++rep) {
    const int idx = rep * 256 + tid;
    const int jr = idx >> 6, d = idx & 63;
    T[jr][d] = kvb[(size_t)(bb * L + jt * 64 + jr) * 2048 + DIM + h * HD + d];
  }
  __syncthreads();
#pragma unroll
  for (int rep = 0; rep < 16; ++rep) {
    const int idx = rep * 256 + tid;
    const int dr = idx >> 6, j = idx & 63;
    vt[(size_t)((bb * NH + h) * HD + dr) * L + jt * 64 + j] = T[j][dr];
  }
}

// ---------------- a1u[b,h,i,q] = sum_p atc1[b,i,p] * U[h,p,q] ----------------
__global__ __launch_bounds__(256) void a1u_kernel(const float* __restrict__ atc1,
                                                  const float* __restrict__ U,
                                                  float* __restrict__ a1u) {
  const int idx = blockIdx.x * 256 + threadIdx.x;
  if (idx >= NB * NH * L * 5) return;
  const int q = idx % 5;
  const int i = (idx / 5) & (L - 1);
  const int h = (idx / (5 * L)) & (NH - 1);
  const int b = idx / (5 * L * NH);
  float s = 0.f;
#pragma unroll
  for (int p = 0; p < 5; ++p)
    s += atc1[(size_t)(b * L + i) * 5 + p] * U[(h * 5 + p) * 5 + q];
  a1u[idx] = s;
}

// ---------------- fused dual-softmax attention v4 ----------------
// grid 4096 1D (XCD-chunked), 256 thr = 4 waves per 16 q-rows.
// P layout (bf16, overwrites f32 score buffer): 16B chunk c of row r stored at
// physical chunk c ^ (r&7)  -> PV ds_read_b128 at the 8-lanes/quad floor.
// V fragments preloaded into registers (T14) to shorten the PV latency chain.
__global__ __launch_bounds__(256, 4) void attn4(
    const u16* __restrict__ qb, const u16* __restrict__ kvb,
    const u16* __restrict__ vt, const float* __restrict__ a1u,
    const float* __restrict__ atc2, const float* __restrict__ mixp,
    u16* __restrict__ attb) {
  __shared__ __align__(16) float Sf[16 * 512];  // 32 KB
  const int tid = threadIdx.x;
  const int wv = tid >> 6;
  const int lane = tid & 63;
  const int ll = lane & 15, lg = lane >> 4;
  const int bid = blockIdx.x;
  const int slot = bid >> 3;
  const int bh = (bid & 7) * 16 + (slot >> 5);  // 16 (b,h) panels per XCD
  const int it = slot & 31;
  const int b = bh >> 4, h = bh & 15;
  const int i0 = it * 16;

  const float ratio = (tanhf(mixp[0]) + 1.0f) * 0.5f;

  // ---- Q fragments ----
  const u16* qp = qb + (size_t)(b * L + i0 + ll) * DIM + h * HD + lg * 8;
  const short8 aq0 = *reinterpret_cast<const short8*>(qp);
  const short8 aq1 = *reinterpret_cast<const short8*>(qp + 32);

  // ---- bio scores upfront; lane owns k-cols [4*lane,+4) and [256+4*lane,+4) ----
  float bs[4][8];
  {
    float r2a[20], r2b[20];
    {
      const float4* pa = reinterpret_cast<const float4*>(atc2 + ((size_t)b * L + 4 * lane) * 5);
      const float4* pb = reinterpret_cast<const float4*>(atc2 + ((size_t)b * L + 256 + 4 * lane) * 5);
#pragma unroll
      for (int u = 0; u < 5; ++u) {
        const float4 ta = pa[u], tb = pb[u];
        r2a[4 * u] = ta.x; r2a[4 * u + 1] = ta.y; r2a[4 * u + 2] = ta.z; r2a[4 * u + 3] = ta.w;
        r2b[4 * u] = tb.x; r2b[4 * u + 1] = tb.y; r2b[4 * u + 2] = tb.z; r2b[4 * u + 3] = tb.w;
      }
    }
    const float* a1p = a1u + ((size_t)(b * NH + h) * L + i0 + wv * 4) * 5;  // uniform
    float a1v[20];
#pragma unroll
    for (int p = 0; p < 20; ++p) a1v[p] = a1p[p];
#pragma unroll
    for (int ri = 0; ri < 4; ++ri) {
#pragma unroll
      for (int j = 0; j < 4; ++j) {
        float sa = 0.f, sb = 0.f;
#pragma unroll
        for (int p = 0; p < 5; ++p) {
          sa += a1v[ri * 5 + p] * r2a[j * 5 + p];
          sb += a1v[ri * 5 + p] * r2b[j * 5 + p];
        }
        bs[ri][j] = sa; bs[ri][j + 4] = sb;
      }
    }
  }

  // ---- std scores: wave wv computes cols [wv*128, +128); row-XOR chunk store ----
#pragma unroll
  for (int jt8 = 0; jt8 < 8; ++jt8) {
    const int jj = wv * 8 + jt8;
    const u16* kp = kvb + (size_t)(b * L + jj * 16 + ll) * 2048 + h * HD + lg * 8;
    const short8 k0 = *reinterpret_cast<const short8*>(kp);
    const short8 k1 = *reinterpret_cast<const short8*>(kp + 32);
    f32x4 s = (f32x4){0.f, 0.f, 0.f, 0.f};
    s = __builtin_amdgcn_mfma_f32_16x16x32_bf16(aq0, k0, s, 0, 0, 0);
    s = __builtin_amdgcn_mfma_f32_16x16x32_bf16(aq1, k1, s, 0, 0, 0);
    const int cfb = jj * 4 + (ll >> 2);
#pragma unroll
    for (int r = 0; r < 4; ++r) {
      const int row = lg * 4 + r;
      Sf[row * 512 + (((cfb ^ (row & 7)) << 2) | (ll & 3))] = s[r] * 0.125f;
    }
  }

  // ---- V preload bank A (kk 0..7) — independent of LDS, issued pre-barrier ----
  const u16* vbase = vt + ((size_t)(b * NH + h) * HD + wv * 16 + ll) * L;
  short8 va[8];
#pragma unroll
  for (int kk = 0; kk < 8; ++kk)
    va[kk] = *reinterpret_cast<const short8*>(vbase + kk * 32 + lg * 8);

  __syncthreads();

  // ---- merged dual softmax: wave wv owns rows wv*4..+3; P -> bf16 in place ----
#pragma unroll
  for (int ri = 0; ri < 4; ++ri) {
    const int i = wv * 4 + ri;
    const int p1 = lane ^ (i & 7);  // stored position of natural f32-chunk `lane`
    const float4 x1 = *reinterpret_cast<const float4*>(&Sf[i * 512 + (p1 << 2)]);
    const float4 x2 = *reinterpret_cast<const float4*>(&Sf[i * 512 + ((64 + p1) << 2)]);
    float e1[8], e2[8];
    e1[0] = __expf(x1.x); e1[1] = __expf(x1.y); e1[2] = __expf(x1.z); e1[3] = __expf(x1.w);
    e1[4] = __expf(x2.x); e1[5] = __expf(x2.y); e1[6] = __expf(x2.z); e1[7] = __expf(x2.w);
#pragma unroll
    for (int j = 0; j < 8; ++j) e2[j] = __expf(bs[ri][j]);
    float l1 = 0.f, l2 = 0.f;
#pragma unroll
    for (int j = 0; j < 8; ++j) { l1 += e1[j]; l2 += e2[j]; }
#pragma unroll
    for (int off = 32; off > 0; off >>= 1) {
      l1 += __shfl_xor(l1, off);
      l2 += __shfl_xor(l2, off);
    }
    const float sc1 = (1.f - ratio) / l1, sc2 = ratio / l2;
    float p[8];
#pragma unroll
    for (int j = 0; j < 8; ++j) p[j] = sc1 * e1[j] + sc2 * e2[j];
    // bf16 P write, chunk-swizzled: elems j=4*lane..+3 -> chunk lane>>1 half lane&1
    // physical chunk = (lane>>1) ^ (i&7); second block (+256 elems) at +512 B.
    char* rowb = reinterpret_cast<char*>(Sf) + i * 2048;
    const int off0 = (((lane >> 1) ^ (i & 7)) << 4) | ((lane & 1) << 3);
    uint2 w0; w0.x = pkbf(p[0], p[1]); w0.y = pkbf(p[2], p[3]);
    uint2 w1; w1.x = pkbf(p[4], p[5]); w1.y = pkbf(p[6], p[7]);
    *reinterpret_cast<uint2*>(rowb + off0) = w0;
    *reinterpret_cast<uint2*>(rowb + 512 + off0) = w1;
  }
  __syncthreads();

  // ---- single PV pass: wave wv owns d-block wv; P read swizzle-compensated ----
  f32x4 O = (f32x4){0.f, 0.f, 0.f, 0.f};
  const char* Pb = reinterpret_cast<const char*>(Sf) + ll * 2048;
  short8 vb[8];
#pragma unroll
  for (int kk = 0; kk < 8; ++kk) {
    vb[kk] = *reinterpret_cast<const short8*>(vbase + (8 + kk) * 32 + lg * 8);  // bank B issue
    const short8 pa = *reinterpret_cast<const short8*>(
        Pb + (((kk * 4 + lg) ^ (ll & 7)) << 4));
    O = __builtin_amdgcn_mfma_f32_16x16x32_bf16(pa, va[kk], O, 0, 0, 0);
  }
#pragma unroll
  for (int kk = 8; kk < 16; ++kk) {
    const short8 pa = *reinterpret_cast<const short8*>(
        Pb + (((kk * 4 + lg) ^ (ll & 7)) << 4));
    O = __builtin_amdgcn_mfma_f32_16x16x32_bf16(pa, vb[kk - 8], O, 0, 0, 0);
  }
#pragma unroll
  for (int r = 0; r < 4; ++r)
    attb[(size_t)(b * L + i0 + lg * 4 + r) * DIM + h * HD + wv * 16 + ll] = f2bf(O[r]);
}

// ---------------- launcher ----------------
extern "C" void kernel_launch(void* const* d_in, const int* in_sizes, int n_in,
                              void* d_out, int out_size, void* d_ws, size_t ws_size,
                              hipStream_t stream) {
  (void)in_sizes; (void)n_in; (void)out_size; (void)ws_size;
  const float* seq1 = (const float*)d_in[0];
  const float* seq2 = (const float*)d_in[1];
  const float* atc1 = (const float*)d_in[2];
  const float* atc2 = (const float*)d_in[3];
  const float* Wq = (const float*)d_in[4];
  const float* bq = (const float*)d_in[5];
  const float* Wk = (const float*)d_in[6];
  const float* bk = (const float*)d_in[7];
  const float* Wv = (const float*)d_in[8];
  const float* bv = (const float*)d_in[9];
  const float* Wo = (const float*)d_in[10];
  const float* bo = (const float*)d_in[11];
  const float* U = (const float*)d_in[12];
  const float* mixp = (const float*)d_in[13];

  char* ws = (char*)d_ws;
  const size_t SEQB = (size_t)ML * DIM * sizeof(u16);   // 8 MiB
  const size_t WB = (size_t)DIM * DIM * sizeof(u16);    // 2 MiB
  size_t o = 0;
  u16* s1b = (u16*)(ws + o); o += SEQB;
  u16* s2b = (u16*)(ws + o); o += SEQB;
  u16* wqb = (u16*)(ws + o); o += WB;
  u16* wkvb = (u16*)(ws + o); o += 2 * WB;              // Wk ; Wv contiguous
  u16* wob = (u16*)(ws + o); o += WB;
  u16* qb = (u16*)(ws + o); o += SEQB;
  u16* kvb = (u16*)(ws + o); o += 2 * SEQB;             // [4096][2048] K|V
  u16* vtb = (u16*)(ws + o); o += SEQB;
  u16* attb = (u16*)(ws + o); o += SEQB;
  float* a1u = (float*)(ws + o); o += (size_t)NB * NH * L * 5 * sizeof(float);

  cvt_all<<<6144, 256, 0, stream>>>(seq1, seq2, Wq, Wk, Wv, Wo, s1b, s2b, wqb,
                                    wkvb, wkvb + (size_t)DIM * DIM, wob);

  gemm_db<64, false, false, 16><<<512, 256, 0, stream>>>(s1b, wqb, bq, bq, qb, DIM, DIM);
  gemm_db<128, false, true, 16><<<512, 256, 0, stream>>>(s2b, wkvb, bk, bv, kvb, 2048, DIM);

  transpose_v<<<dim3(L / 64, NH, NB), 256, 0, stream>>>(kvb, vtb);
  a1u_kernel<<<(NB * NH * L * 5 + 255) / 256, 256, 0, stream>>>(atc1, U, a1u);

  attn4<<<4096, 256, 0, stream>>>(qb, kvb, vtb, a1u, atc2, mixp, attb);

  gemm_db<64, true, false, 16><<<512, 256, 0, stream>>>(attb, wob, bo, bo, (float*)d_out, DIM, DIM);
}